// Round 8
// baseline (150.000 us; speedup 1.0000x reference)
//
#include <hip/hip_runtime.h>

// DiscriminatorIndependent: 1024 tiny MLPs (2->4->1, relu), B=16384.
//
// Ledger: R0=R6=R11=41.2-41.9us across wildly different structures; traffic
// (R7), occupancy (R6), counted-vmcnt pipelining (R9), DS-pipe work (R11:
// DPP reduction, -75% DS, zero delta) all exonerated. Every floor kernel
// moves the payload through global_load_lds at a constant ~3.1 TB/s.
//
// R12 theory: the LDS-DMA engine has a small per-CU outstanding-request
// budget (~8-16 x 1KB); at ~700ns mixed L3/HBM latency that IS ~3 TB/s.
// (m97 GEMM gets ~14 TB/s from the same intrinsic because L2-hot ~200ns.)
// Registers bypass that queue, but the compiler serializes register loads
// (R5: dependent-chain, one exposed latency per use). Untested cell:
// asm-FORCED batching -- 16 back-to-back global_load_dword per thread
// (8 rows x 2 arrays, coalesced), one s_waitcnt vmcnt(0) whose asm TIES all
// 16 dest registers ("+v") so no consumer can hoist above it (rule #18:
// "memory" alone does not order register-only FMAs). 4KB/wave in flight,
// ~32 waves/CU -> 128KB/CU, Little's law >> 6 TB/s. No LDS staging, no
// barrier before the epilogue combine. Everything else is R11 verbatim.

constexpr int N_MLP = 1024;
constexpr int BATCH = 16384;
constexpr int ROWS = 8;        // batch rows per block
constexpr int NTHREADS = 256;  // 4 waves
constexpr int QN = 256;        // MLPs per block (quarter of N)
constexpr int NQ = N_MLP / QN; // 4 quarters

// v += value from DPP-permuted v (invalid source lanes contribute old=0).
template<int CTRL, int ROW_MASK>
__device__ __forceinline__ float dpp_add(float v) {
    int s = __builtin_amdgcn_update_dpp(0, __float_as_int(v),
                                        CTRL, ROW_MASK, 0xf, false);
    return v + __int_as_float(s);
}

// Full wave64 sum on the VALU pipe; total ends in lane 63.
__device__ __forceinline__ float wave_sum_dpp(float v) {
    v = dpp_add<0x111, 0xf>(v);   // row_shr:1
    v = dpp_add<0x112, 0xf>(v);   // row_shr:2
    v = dpp_add<0x114, 0xf>(v);   // row_shr:4
    v = dpp_add<0x118, 0xf>(v);   // row_shr:8
    v = dpp_add<0x142, 0xa>(v);   // row_bcast:15
    v = dpp_add<0x143, 0xc>(v);   // row_bcast:31
    return v;
}

__global__ __launch_bounds__(256)
void zero_out_kernel(float* __restrict__ out) {
    out[blockIdx.x * 256 + threadIdx.x] = 0.0f;
}

__global__ __launch_bounds__(NTHREADS, 4)
void disc_mlp_kernel(const float* __restrict__ x,
                     const float* __restrict__ xa,
                     const float* __restrict__ W1,
                     const float* __restrict__ b1,
                     const float* __restrict__ W2,
                     const float* __restrict__ b2,
                     float* __restrict__ out)
{
    __shared__ float red[NTHREADS / 64][ROWS];

    const int t    = threadIdx.x;
    const int lane = t & 63;
    const int wave = t >> 6;
    const int q  = blockIdx.x & (NQ - 1);  // n-quarter
    const int rb = blockIdx.x >> 2;        // row tile
    const int b0 = rb * ROWS;
    const int n  = q * QN + t;             // this thread's MLP

    // ---- payload: 16 back-to-back coalesced dword loads, asm-forced ----
    const float* bx = x  + (size_t)b0 * N_MLP + n;   // this thread's column, row 0
    const float* ba = xa + (size_t)b0 * N_MLP + n;
    float vx[ROWS], va[ROWS];
#pragma unroll
    for (int r = 0; r < ROWS; ++r) {
        asm volatile("global_load_dword %0, %1, off"
                     : "=v"(vx[r]) : "v"(bx + (size_t)r * N_MLP));
        asm volatile("global_load_dword %0, %1, off"
                     : "=v"(va[r]) : "v"(ba + (size_t)r * N_MLP));
    }

    // ---- params (compiler-scheduled; L1/L2-hot, needed only after wait) ----
    const float4 p0 = reinterpret_cast<const float4*>(W1)[(size_t)n * 2];
    const float4 p1 = reinterpret_cast<const float4*>(W1)[(size_t)n * 2 + 1];
    const float4 bb = reinterpret_cast<const float4*>(b1)[n];
    const float4 ww = reinterpret_cast<const float4*>(W2)[n];
    const float  b2r = b2[n];

    // ---- one wait for all 16 payload loads; dest regs tied through the asm
    // so no consumer can be scheduled above it (rule #18) ----
    asm volatile("s_waitcnt vmcnt(0)"
                 : "+v"(vx[0]), "+v"(vx[1]), "+v"(vx[2]), "+v"(vx[3]),
                   "+v"(vx[4]), "+v"(vx[5]), "+v"(vx[6]), "+v"(vx[7]),
                   "+v"(va[0]), "+v"(va[1]), "+v"(va[2]), "+v"(va[3]),
                   "+v"(va[4]), "+v"(va[5]), "+v"(va[6]), "+v"(va[7])
                 :: "memory");
    __builtin_amdgcn_sched_barrier(0);

    const float A[4]   = {p0.x, p0.z, p1.x, p1.z};
    const float C[4]   = {p0.y, p0.w, p1.y, p1.w};
    const float B1r[4] = {bb.x, bb.y, bb.z, bb.w};
    const float V[4]   = {ww.x, ww.y, ww.z, ww.w};

    // ---- compute + DPP wave-reduce (no DS until epilogue) ----
#pragma unroll
    for (int r = 0; r < ROWS; ++r) {
        float s = b2r;
#pragma unroll
        for (int j = 0; j < 4; ++j) {
            float h = fmaf(A[j], vx[r], fmaf(C[j], va[r], B1r[j]));
            h = fmaxf(h, 0.0f);
            s = fmaf(V[j], h, s);
        }
        const float v = wave_sum_dpp(s);
        if (lane == 63) red[wave][r] = v;
    }
    __syncthreads();
    if (t < ROWS) {
        float s = (red[0][t] + red[1][t]) + (red[2][t] + red[3][t]);
        atomicAdd(out + b0 + t, s * (1.0f / (float)N_MLP));
    }
}

extern "C" void kernel_launch(void* const* d_in, const int* in_sizes, int n_in,
                              void* d_out, int out_size, void* d_ws, size_t ws_size,
                              hipStream_t stream) {
    const float* x  = (const float*)d_in[0];
    const float* xa = (const float*)d_in[1];
    const float* W1 = (const float*)d_in[2];
    const float* b1 = (const float*)d_in[3];
    const float* W2 = (const float*)d_in[4];
    const float* b2 = (const float*)d_in[5];
    float* out = (float*)d_out;

    zero_out_kernel<<<BATCH / 256, 256, 0, stream>>>(out);
    disc_mlp_kernel<<<(BATCH / ROWS) * NQ, NTHREADS, 0, stream>>>(x, xa, W1, b1, W2, b2, out);
}

// Round 9
// 149.427 us; speedup vs baseline: 1.0038x; 1.0038x over previous
//
#include <hip/hip_runtime.h>

// DiscriminatorIndependent: 1024 tiny MLPs (2->4->1, relu), B=16384.
//
// Ledger: R0=R6=R11 = 41.2-41.9us (LDS-DMA payload), R12 = 45.2us
// (asm-batched register payload) -- all ~3.0-3.1 TB/s read. R11-vs-R12
// shows 4x instruction-count at equal bytes = equal BW -> the cap is
// outstanding BYTES (MSHR-like), not instructions. m13's "6.29 TB/s copy"
// must be read+write total (else >8TB/s pins) -> reads there also ~3.15;
// fillBuffer (this round) proves pure WRITES do 6.6 TB/s. Every read
// stream pins at ~3.1 TB/s regardless of path.
//
// R13: test whether the LDS-DMA engine and the register-load path have
// SEPARATE outstanding-read pools: x via global_load_lds (R11 pattern),
// xa via 8 asm-batched global_load_dword into registers (R12 pattern),
// issued back-to-back so both queues fill concurrently; one tied
// s_waitcnt vmcnt(0) + barrier; compute reads x from LDS, xa from regs.
// Separate pools -> ~2x outstanding bytes -> ~26-31us. Shared -> flat
// 41-45us -> read-path outstanding-capacity roofline, declare done.

constexpr int N_MLP = 1024;
constexpr int BATCH = 16384;
constexpr int ROWS = 8;        // batch rows per block
constexpr int NTHREADS = 256;  // 4 waves
constexpr int QN = 256;        // MLPs per block (quarter of N)
constexpr int NQ = N_MLP / QN; // 4 quarters

typedef __attribute__((address_space(3))) void lds_void;
typedef const __attribute__((address_space(1))) void gbl_void;

// v += value from DPP-permuted v (invalid source lanes contribute old=0).
template<int CTRL, int ROW_MASK>
__device__ __forceinline__ float dpp_add(float v) {
    int s = __builtin_amdgcn_update_dpp(0, __float_as_int(v),
                                        CTRL, ROW_MASK, 0xf, false);
    return v + __int_as_float(s);
}

// Full wave64 sum on the VALU pipe; total ends in lane 63.
__device__ __forceinline__ float wave_sum_dpp(float v) {
    v = dpp_add<0x111, 0xf>(v);   // row_shr:1
    v = dpp_add<0x112, 0xf>(v);   // row_shr:2
    v = dpp_add<0x114, 0xf>(v);   // row_shr:4
    v = dpp_add<0x118, 0xf>(v);   // row_shr:8
    v = dpp_add<0x142, 0xa>(v);   // row_bcast:15
    v = dpp_add<0x143, 0xc>(v);   // row_bcast:31
    return v;
}

__global__ __launch_bounds__(256)
void zero_out_kernel(float* __restrict__ out) {
    out[blockIdx.x * 256 + threadIdx.x] = 0.0f;
}

__global__ __launch_bounds__(NTHREADS, 8)
void disc_mlp_kernel(const float* __restrict__ x,
                     const float* __restrict__ xa,
                     const float* __restrict__ W1,
                     const float* __restrict__ b1,
                     const float* __restrict__ W2,
                     const float* __restrict__ b2,
                     float* __restrict__ out)
{
    __shared__ float xbuf[ROWS * QN];   // 8 KB (x only)
    __shared__ float red[NTHREADS / 64][ROWS];

    const int t    = threadIdx.x;
    const int lane = t & 63;
    const int wave = t >> 6;
    const int q  = blockIdx.x & (NQ - 1);  // n-quarter
    const int rb = blockIdx.x >> 2;        // row tile
    const int b0 = rb * ROWS;
    const int n  = q * QN + t;             // this thread's MLP

    // ---- path 1: x rows -> LDS via async DMA (wave w stages rows 2w,2w+1) ----
    const float* gx = x + (size_t)b0 * N_MLP + q * QN;
#pragma unroll
    for (int i = 0; i < ROWS / 4; ++i) {
        const int r = wave * (ROWS / 4) + i;
        const float* srcx = gx + (size_t)r * N_MLP + lane * 4;
        __builtin_amdgcn_global_load_lds((gbl_void*)srcx,
                                         (lds_void*)&xbuf[r * QN + lane * 4],
                                         16, 0, 0);
    }

    // ---- path 2: xa column -> registers, 8 back-to-back asm loads ----
    const float* ba = xa + (size_t)b0 * N_MLP + n;
    float va[ROWS];
#pragma unroll
    for (int r = 0; r < ROWS; ++r) {
        asm volatile("global_load_dword %0, %1, off"
                     : "=v"(va[r]) : "v"(ba + (size_t)r * N_MLP));
    }

    // ---- params (compiler-scheduled; L1/L2-hot) ----
    const float4 p0 = reinterpret_cast<const float4*>(W1)[(size_t)n * 2];
    const float4 p1 = reinterpret_cast<const float4*>(W1)[(size_t)n * 2 + 1];
    const float4 bb = reinterpret_cast<const float4*>(b1)[n];
    const float4 ww = reinterpret_cast<const float4*>(W2)[n];
    const float  b2r = b2[n];

    // ---- one wait for both paths; va regs tied so consumers can't hoist ----
    asm volatile("s_waitcnt vmcnt(0)"
                 : "+v"(va[0]), "+v"(va[1]), "+v"(va[2]), "+v"(va[3]),
                   "+v"(va[4]), "+v"(va[5]), "+v"(va[6]), "+v"(va[7])
                 :: "memory");
    __builtin_amdgcn_sched_barrier(0);
    __syncthreads();   // xbuf staged by other waves now visible

    const float A[4]   = {p0.x, p0.z, p1.x, p1.z};
    const float C[4]   = {p0.y, p0.w, p1.y, p1.w};
    const float B1r[4] = {bb.x, bb.y, bb.z, bb.w};
    const float V[4]   = {ww.x, ww.y, ww.z, ww.w};

    // ---- compute (x from LDS, xa from regs) + DPP wave-reduce ----
#pragma unroll
    for (int r = 0; r < ROWS; ++r) {
        const float xe = xbuf[r * QN + t];
        float s = b2r;
#pragma unroll
        for (int j = 0; j < 4; ++j) {
            float h = fmaf(A[j], xe, fmaf(C[j], va[r], B1r[j]));
            h = fmaxf(h, 0.0f);
            s = fmaf(V[j], h, s);
        }
        const float v = wave_sum_dpp(s);
        if (lane == 63) red[wave][r] = v;
    }
    __syncthreads();
    if (t < ROWS) {
        float s = (red[0][t] + red[1][t]) + (red[2][t] + red[3][t]);
        atomicAdd(out + b0 + t, s * (1.0f / (float)N_MLP));
    }
}

extern "C" void kernel_launch(void* const* d_in, const int* in_sizes, int n_in,
                              void* d_out, int out_size, void* d_ws, size_t ws_size,
                              hipStream_t stream) {
    const float* x  = (const float*)d_in[0];
    const float* xa = (const float*)d_in[1];
    const float* W1 = (const float*)d_in[2];
    const float* b1 = (const float*)d_in[3];
    const float* W2 = (const float*)d_in[4];
    const float* b2 = (const float*)d_in[5];
    float* out = (float*)d_out;

    zero_out_kernel<<<BATCH / 256, 256, 0, stream>>>(out);
    disc_mlp_kernel<<<(BATCH / ROWS) * NQ, NTHREADS, 0, stream>>>(x, xa, W1, b1, W2, b2, out);
}